// Round 1
// baseline (116.145 us; speedup 1.0000x reference)
//
#include <hip/hip_runtime.h>

// Problem shape (fixed): n=32, m=16, p=1024, d=512.
// out[n,p,d] = feat[n,p,d] * mean_m(task[n,m,p])
//
// Single-kernel structure (round 5): the old two-kernel split (mean table in
// ws, then stream) paid a second dispatch + a full dependency bubble between
// the 2MB reduction and the 128MB stream. Here each wave computes its own
// row mean inline: idx4>>7 is wave-uniform (128 float4/row, 64 lanes/wave),
// so readfirstlane makes the 16 task loads SCALAR (s_load_dword, constant
// cache, lgkmcnt) — zero VMEM pressure added to the stream. No LDS, no
// __syncthreads, no nt stores (those were the round-4 +4us regression).
// Task is 2MB -> L2-resident; each value re-read by only 2 waves.
//
// Summation order matches the old mean_kernel exactly (sequential m, *1/16)
// so numerics are unchanged.

#define N_DIM 32
#define M_DIM 16
#define P_DIM 1024
#define D_DIM 512
#define NP    (N_DIM * P_DIM)            // 32768 rows
#define TOTAL4 (NP * (D_DIM / 4))        // 4,194,304 float4 elements

__global__ __launch_bounds__(256) void fused_scale_kernel(
    const float* __restrict__ task,      // [n, m, p]
    const float* __restrict__ feat,      // [n*p, d]
    float* __restrict__ out)             // [n*p, d]
{
    const int idx4 = blockIdx.x * 256 + threadIdx.x;   // float4 index

    // Row index is uniform across each 64-lane wave: 128 float4s per row.
    // readfirstlane proves uniformity -> scalar (s_load) task reads.
    const int row = __builtin_amdgcn_readfirstlane(idx4 >> 7);  // 0..NP-1
    const int n = row >> 10;                                    // / P_DIM
    const int p = row & (P_DIM - 1);

    const float* t = task + (size_t)n * (M_DIM * P_DIM) + p;
    float s = 0.0f;
#pragma unroll
    for (int m = 0; m < M_DIM; ++m) {
        s += t[(size_t)m * P_DIM];       // wave-uniform -> s_load_dword
    }
    const float mean = s * (1.0f / (float)M_DIM);

    float4 v = ((const float4*)feat)[idx4];
    v.x *= mean; v.y *= mean; v.z *= mean; v.w *= mean;
    ((float4*)out)[idx4] = v;
}

extern "C" void kernel_launch(void* const* d_in, const int* in_sizes, int n_in,
                              void* d_out, int out_size, void* d_ws, size_t ws_size,
                              hipStream_t stream) {
    const float* task = (const float*)d_in[0];   // [32,16,1024] fp32
    const float* feat = (const float*)d_in[1];   // [32,1024,512] fp32
    float* out  = (float*)d_out;                 // [32,1024,512] fp32
    (void)d_ws; (void)ws_size;                   // workspace no longer needed

    fused_scale_kernel<<<dim3(TOTAL4 / 256), dim3(256), 0, stream>>>(task, feat, out);
}